// Round 9
// baseline (86.012 us; speedup 1.0000x reference)
//
#include <hip/hip_runtime.h>
#include <stdint.h>

#define NB 32768   // batch
#define NN 128     // stages

typedef __attribute__((ext_vector_type(8))) short bf16x8;
typedef __attribute__((ext_vector_type(4))) float f32x4;

__device__ __forceinline__ short f2bf(float v) {
    uint32_t u = __float_as_uint(v);
    u += 0x7FFF + ((u >> 16) & 1);   // RNE
    return (short)(u >> 16);
}

// d_ws layout:
//  shorts [0, 8192*8)      : weight fragment streams (bf16x8 chunks):
//     B1: ci=(c16*4+t)*64+l ; S1: ci=4096+(c16*2+t2)*64+l ; S2: ci=6144+...
//  shorts [65536, 65536+1536): float consts: [0,256)=bx, [256,512)=Wy[c][64],
//                              [512,768)=Wy[c][129]
//  bytes  [196608, 327680) : Pg[32768] float  = phi[r][64] (+-1.0f)
//  bytes  [524288, +8.39MB): Pf: phi A-fragments, bf16x8 chunk index
//                            ((rb*4 + t)*4 + rf)*64 + l   (rb<512 row-blocks)
#define WS_CONST_SHORTOFF 65536
#define WS_PG_BYTEOFF     196608
#define WS_PF_BYTEOFF     524288

// 547 blocks x 256. Blocks 0..511: phi part (64 rows each). 512..546: weights.
__global__ void puf_prep(const float* __restrict__ x, const float* __restrict__ Wx,
                         const float* __restrict__ bx, const float* __restrict__ Wy,
                         uint16_t* __restrict__ Wc) {
    const int bid = blockIdx.x, tid = threadIdx.x;
    if (bid < 512) {
        __shared__ __align__(16) uint16_t As[64 * 128];
        __shared__ float Sg[64];
        const int w = tid >> 6, l = tid & 63;
        const int l15 = l & 15, l4 = l >> 4;
        const int row0 = bid * 64;

        float xa[16], xb[16];
#pragma unroll
        for (int i = 0; i < 16; ++i) {
            int grow = row0 + w * 16 + i;
            xa[i] = x[grow * NN + l];
            xb[i] = x[grow * NN + 64 + l];
        }
#pragma unroll
        for (int i = 0; i < 16; ++i) {
            int r = w * 16 + i;
            unsigned long long m0 = __ballot(xa[i] > 0.5f);  // x[r][0..63]
            unsigned long long m1 = __ballot(xb[i] > 0.5f);  // x[r][64..127]
            int onesHi = __popcll(m1);
            int parLo = (__popcll(m0 >> l) + onesHi) & 1;    // parity x[r][l..127]
            int parHi = (__popcll(m1 >> l)) & 1;             // parity x[r][64+l..127]
            int sw = (r & 7) << 3;
            As[r * 128 + (l ^ sw)]        = parLo ? 0xBF80u : 0x3F80u;
            As[r * 128 + (64 + (l ^ sw))] = parHi ? 0xBF80u : 0x3F80u;
            if (l == 0) Sg[r] = (onesHi & 1) ? -1.0f : 1.0f;
        }
        __syncthreads();

        // export A-fragments: wave w handles K-tile t = w
        bf16x8* Pf8 = (bf16x8*)((char*)Wc + WS_PF_BYTEOFF);
        const int k = w * 32 + l4 * 8;
#pragma unroll
        for (int rf = 0; rf < 4; ++rf) {
            int r = rf * 16 + l15;
            bf16x8 af = *(const bf16x8*)&As[r * 128 + ((k & 64) | ((k & 63) ^ ((r & 7) << 3)))];
            Pf8[((bid * 4 + w) * 4 + rf) * 64 + l] = af;
        }
        float* Pg = (float*)((char*)Wc + WS_PG_BYTEOFF);
        if (tid < 64) Pg[row0 + tid] = Sg[tid];
    } else {
        int gid = (bid - 512) * 256 + tid;   // 8960 items
        if (gid < 8192) {
            int l = gid & 63;
            int l15 = l & 15, k8 = (l >> 4) * 8;
            const float* src;
            if (gid < 4096) {
                int c16 = gid >> 8, t = (gid >> 6) & 3;
                src = Wx + (c16 * 16 + l15) * NN + t * 32 + k8;
            } else if (gid < 6144) {
                int j = gid - 4096;
                int c16 = j >> 7, t2 = (j >> 6) & 1;
                src = Wy + (c16 * 16 + l15) * 130 + t2 * 32 + k8;
            } else {
                int j = gid - 6144;
                int c16 = j >> 7, t2 = (j >> 6) & 1;
                src = Wy + (c16 * 16 + l15) * 130 + 65 + t2 * 32 + k8;
            }
            bf16x8 pk;
#pragma unroll
            for (int e = 0; e < 8; ++e) pk[e] = f2bf(src[e]);
            *(bf16x8*)&Wc[gid * 8] = pk;
        } else if (gid < 8960) {
            int j = gid - 8192;                 // 0..767
            int c = j & 255, sel = j >> 8;
            float v = (sel == 0) ? bx[c] : ((sel == 1) ? Wy[c * 130 + 64] : Wy[c * 130 + 129]);
            ((float*)(Wc + WS_CONST_SHORTOFF))[j] = v;
        }
    }
}

// 2048 blocks x 256 threads, NO LDS, NO barrier, single fused A-pass:
// B2's S1/S2 GEMMs don't depend on xo, so each A-fragment tile feeds both
// B1 and B2 MFMAs and then dies -> peak ~100 VGPR, no spills, 4 waves/EU.
// Block: rg=bid&511 (64 rows), cg=bid>>9 (64 of 256 cols); rg,rg+512,...
// share A-frags on the same XCD (512%8==0). Wave w: 64 rows x 16 cols.
__global__ __launch_bounds__(256, 4) void puf_main(
    const uint16_t* __restrict__ Wc, float* __restrict__ out)
{
    const int tid = threadIdx.x;
    const int w = tid >> 6, l = tid & 63;
    const int l15 = l & 15, l4 = l >> 4;
    const int bid = blockIdx.x;
    const int rg = bid & 511, cg = bid >> 9;
    const int row0 = rg * 64;
    const int c16 = cg * 4 + w;

    const bf16x8* wc8 = (const bf16x8*)Wc;
    const float*  cw  = (const float*)(Wc + WS_CONST_SHORTOFF);
    const float*  Pg  = (const float*)((const char*)Wc + WS_PG_BYTEOFF);
    const bf16x8* Pf8 = (const bf16x8*)((const char*)Wc + WS_PF_BYTEOFF);

    const f32x4 zero4 = {0.0f, 0.0f, 0.0f, 0.0f};
    f32x4 acc1[4], aS1[4], aS2[4];
#pragma unroll
    for (int a = 0; a < 4; ++a) { acc1[a] = zero4; aS1[a] = zero4; aS2[a] = zero4; }

    // ---- single pass over the 4 A-fragment k-tiles: B1 + B2 MFMAs per tile ----
#pragma unroll
    for (int t = 0; t < 4; ++t) {
        bf16x8 aF[4];
#pragma unroll
        for (int rf = 0; rf < 4; ++rf)
            aF[rf] = Pf8[((rg * 4 + t) * 4 + rf) * 64 + l];
        bf16x8 fB = wc8[(c16 * 4 + t) * 64 + l];
        bf16x8 fS = (t < 2) ? wc8[4096 + (c16 * 2 + t) * 64 + l]
                            : wc8[6144 + (c16 * 2 + (t - 2)) * 64 + l];
        __builtin_amdgcn_s_setprio(1);
#pragma unroll
        for (int rf = 0; rf < 4; ++rf)
            acc1[rf] = __builtin_amdgcn_mfma_f32_16x16x32_bf16(aF[rf], fB, acc1[rf], 0, 0, 0);
        if (t < 2) {
#pragma unroll
            for (int rf = 0; rf < 4; ++rf)
                aS1[rf] = __builtin_amdgcn_mfma_f32_16x16x32_bf16(aF[rf], fS, aS1[rf], 0, 0, 0);
        } else {
#pragma unroll
            for (int rf = 0; rf < 4; ++rf)
                aS2[rf] = __builtin_amdgcn_mfma_f32_16x16x32_bf16(aF[rf], fS, aS2[rf], 0, 0, 0);
        }
        __builtin_amdgcn_s_setprio(0);
    }

    // ---- constants (L2-hot), loaded only for the epilogue ----
    const int col = c16 * 16 + l15;
    const float bxv = cw[col], piv = cw[256 + col], eps = cw[512 + col];

    // ---- B1 epilogue in registers: xo[rf][q] ----
    float xo[4][4];
#pragma unroll
    for (int rf = 0; rf < 4; ++rf) {
        float p[4];
#pragma unroll
        for (int q = 0; q < 4; ++q) p[q] = acc1[rf][q] + bxv;
#pragma unroll
        for (int q = 0; q < 4; ++q) {
            p[q] *= __shfl_xor(p[q], 1);
            p[q] *= __shfl_xor(p[q], 2);
            p[q] *= __shfl_xor(p[q], 4);
        }
#pragma unroll
        for (int q = 0; q < 4; ++q) {
            float sig = 1.0f / (1.0f + __expf(-p[q]));
            xo[rf][q] = 1.0f - 2.0f * sig;
        }
    }

    // ---- B2 epilogue: combine, product over ky, sigmoid, store ----
#pragma unroll
    for (int rf = 0; rf < 4; ++rf) {
        f32x4 sg = *(const f32x4*)&Pg[row0 + rf * 16 + l4 * 4];
        float p[4];
#pragma unroll
        for (int q = 0; q < 4; ++q) {
            float xov = xo[rf][q];
            float s1 = aS1[rf][q] + sg[q] * piv;
            float s2 = aS2[rf][q] + eps;
            p[q] = xov * s1 + fabsf(xov) * s2;
        }
#pragma unroll
        for (int q = 0; q < 4; ++q) {
            p[q] *= __shfl_xor(p[q], 1);
            p[q] *= __shfl_xor(p[q], 2);
            p[q] *= __shfl_xor(p[q], 4);
        }
        if ((l & 7) == 0) {
            f32x4 o;
#pragma unroll
            for (int q = 0; q < 4; ++q) o[q] = 1.0f / (1.0f + __expf(-p[q]));
            int m = c16 * 2 + (l15 >> 3);
            *(f32x4*)&out[m * NB + row0 + rf * 16 + l4 * 4] = o;
        }
    }
}

extern "C" void kernel_launch(void* const* d_in, const int* in_sizes, int n_in,
                              void* d_out, int out_size, void* d_ws, size_t ws_size,
                              hipStream_t stream) {
    const float* x  = (const float*)d_in[0];
    const float* Wx = (const float*)d_in[1];
    const float* bx = (const float*)d_in[2];
    const float* Wy = (const float*)d_in[3];
    float* out = (float*)d_out;
    uint16_t* Wc = (uint16_t*)d_ws;   // ~8.9 MB used

    puf_prep<<<dim3(547), dim3(256), 0, stream>>>(x, Wx, bx, Wy, Wc);
    puf_main<<<dim3(2048), dim3(256), 0, stream>>>(Wc, out);
}